// Round 1
// baseline (534.636 us; speedup 1.0000x reference)
//
#include <hip/hip_runtime.h>

// TripletLoss on MI355X.
// N=8192 rows, D=256 features, labels int32 (JAX default x64-disabled -> int32).
// loss = mean(relu(MARGIN + dist_ap - dist_an)) with hard mining per row.
//
// Pass 0: sq-norms per row, init ap=0 / an=1e6 (ws re-poisoned each launch), zero out.
// Pass 1: fused tiled fp32 Gram-GEMM (128x128 tile, 8x8 microtile, BK=32) with
//         distance epilogue + per-row masked max/min, merged via integer atomics
//         (float>=0 bit pattern preserves ordering).
// Pass 2: per-row loss -> scalar mean via atomicAdd.

constexpr int N = 8192;
constexpr int D = 256;
constexpr float MARGIN = 0.3f;
constexpr float NEG_FALLBACK = 1e6f;

constexpr int BI = 128;
constexpr int BJ = 128;
constexpr int BK = 32;
constexpr int JSPLIT = 8;
constexpr int JRANGE = N / JSPLIT;          // 1024 columns per block
constexpr int LDS_STRIDE = BI + 4;          // 132: rows stay 16B-aligned for float4 reads

__global__ void tl_pass0(const float* __restrict__ feat,
                         float* __restrict__ norms,
                         float* __restrict__ ap,
                         float* __restrict__ an,
                         float* __restrict__ out) {
  int row = blockIdx.x * 4 + (threadIdx.x >> 6);
  int lane = threadIdx.x & 63;
  float4 f = reinterpret_cast<const float4*>(feat + (size_t)row * D)[lane];
  float s = f.x * f.x + f.y * f.y + f.z * f.z + f.w * f.w;
#pragma unroll
  for (int off = 32; off > 0; off >>= 1) s += __shfl_down(s, off, 64);
  if (lane == 0) {
    norms[row] = s;
    ap[row] = 0.0f;           // max over positives; dists >= 0, ref gives 0 when none
    an[row] = NEG_FALLBACK;   // min over negatives; ref fallback 1e6 when none
  }
  if (row == 0 && lane == 0) out[0] = 0.0f;
}

__global__ __launch_bounds__(256, 2)
void tl_pass1(const float* __restrict__ feat, const int* __restrict__ labels,
              const float* __restrict__ norms,
              unsigned int* __restrict__ ap, unsigned int* __restrict__ an) {
  __shared__ float As[BK][LDS_STRIDE];
  __shared__ float Bs[BK][LDS_STRIDE];

  const int tid = threadIdx.x;
  const int tx = tid & 15;       // 16 col-groups
  const int ty = tid >> 4;       // 16 row-groups
  const int ib0 = blockIdx.y * BI;
  const int jbase = blockIdx.x * JRANGE;

  // This thread's 8 rows: ty*4 + {0..3} and 64 + ty*4 + {0..3}
  float ni[8];
  int li[8];
  int ri[8];
#pragma unroll
  for (int a = 0; a < 8; ++a) {
    int r = ty * 4 + (a & 3) + ((a >> 2) << 6);
    ri[a] = ib0 + r;
    ni[a] = norms[ri[a]];
    li[a] = labels[ri[a]];
  }
  float apv[8], anv[8];
#pragma unroll
  for (int a = 0; a < 8; ++a) { apv[a] = 0.0f; anv[a] = NEG_FALLBACK; }

  for (int jt = 0; jt < JRANGE; jt += BJ) {
    const int jb = jbase + jt;
    float acc[8][8];
#pragma unroll
    for (int a = 0; a < 8; ++a)
#pragma unroll
      for (int b = 0; b < 8; ++b) acc[a][b] = 0.0f;

    for (int kc = 0; kc < D; kc += BK) {
      // Stage A (block rows) and B (current j-rows) tiles, transposed: As[k][i]
#pragma unroll
      for (int u = 0; u < 4; ++u) {
        int lin = tid + u * 256;
        int row = lin >> 3;      // 0..127
        int c4 = lin & 7;        // float4 index within BK
        float4 va = *reinterpret_cast<const float4*>(
            feat + (size_t)(ib0 + row) * D + kc + c4 * 4);
        As[c4 * 4 + 0][row] = va.x;
        As[c4 * 4 + 1][row] = va.y;
        As[c4 * 4 + 2][row] = va.z;
        As[c4 * 4 + 3][row] = va.w;
        float4 vb = *reinterpret_cast<const float4*>(
            feat + (size_t)(jb + row) * D + kc + c4 * 4);
        Bs[c4 * 4 + 0][row] = vb.x;
        Bs[c4 * 4 + 1][row] = vb.y;
        Bs[c4 * 4 + 2][row] = vb.z;
        Bs[c4 * 4 + 3][row] = vb.w;
      }
      __syncthreads();

#pragma unroll 8
      for (int k = 0; k < BK; ++k) {
        float4 a0 = *reinterpret_cast<const float4*>(&As[k][ty * 4]);
        float4 a1 = *reinterpret_cast<const float4*>(&As[k][64 + ty * 4]);
        float4 b0 = *reinterpret_cast<const float4*>(&Bs[k][tx * 4]);
        float4 b1 = *reinterpret_cast<const float4*>(&Bs[k][64 + tx * 4]);
        float av[8] = {a0.x, a0.y, a0.z, a0.w, a1.x, a1.y, a1.z, a1.w};
        float bv[8] = {b0.x, b0.y, b0.z, b0.w, b1.x, b1.y, b1.z, b1.w};
#pragma unroll
        for (int a = 0; a < 8; ++a)
#pragma unroll
          for (int b = 0; b < 8; ++b) acc[a][b] = fmaf(av[a], bv[b], acc[a][b]);
      }
      __syncthreads();
    }

    // Epilogue for this j-tile: dots -> distances -> masked max/min
#pragma unroll
    for (int b = 0; b < 8; ++b) {
      int cj = jb + tx * 4 + (b & 3) + ((b >> 2) << 6);
      float nj = norms[cj];
      int lj = labels[cj];
#pragma unroll
      for (int a = 0; a < 8; ++a) {
        float sq = ni[a] + nj - 2.0f * acc[a][b];
        sq = fmaxf(sq, 0.0f);
        float dist = sqrtf(sq);
        bool same = (li[a] == lj);
        if (same) {
          if (ri[a] != cj) apv[a] = fmaxf(apv[a], dist);  // exclude diagonal
        } else {
          anv[a] = fminf(anv[a], dist);
        }
      }
    }
  }

  // Intra-block reduction across the 16 tx threads sharing each row, then
  // global merge. Reuse As as scratch (128 rows x 16 = 8 KB <= 16.9 KB).
  __syncthreads();
  float* red = &As[0][0];
#pragma unroll
  for (int a = 0; a < 8; ++a) {
    int r = ty * 4 + (a & 3) + ((a >> 2) << 6);
    red[r * 16 + tx] = apv[a];
  }
  __syncthreads();
  if (tid < 128) {
    float m = red[tid * 16];
#pragma unroll
    for (int t = 1; t < 16; ++t) m = fmaxf(m, red[tid * 16 + t]);
    atomicMax(&ap[ib0 + tid], __float_as_uint(m));   // nonneg float bits: order-preserving
  }
  __syncthreads();
#pragma unroll
  for (int a = 0; a < 8; ++a) {
    int r = ty * 4 + (a & 3) + ((a >> 2) << 6);
    red[r * 16 + tx] = anv[a];
  }
  __syncthreads();
  if (tid < 128) {
    float m = red[tid * 16];
#pragma unroll
    for (int t = 1; t < 16; ++t) m = fminf(m, red[tid * 16 + t]);
    atomicMin(&an[ib0 + tid], __float_as_uint(m));
  }
}

__global__ void tl_pass2(const float* __restrict__ ap, const float* __restrict__ an,
                         float* __restrict__ out) {
  int r = blockIdx.x * 256 + threadIdx.x;
  float v = fmaxf(0.0f, MARGIN + ap[r] - an[r]) * (1.0f / (float)N);
#pragma unroll
  for (int off = 32; off > 0; off >>= 1) v += __shfl_down(v, off, 64);
  __shared__ float red[4];
  int lane = threadIdx.x & 63;
  int w = threadIdx.x >> 6;
  if (lane == 0) red[w] = v;
  __syncthreads();
  if (threadIdx.x == 0) atomicAdd(out, red[0] + red[1] + red[2] + red[3]);
}

extern "C" void kernel_launch(void* const* d_in, const int* in_sizes, int n_in,
                              void* d_out, int out_size, void* d_ws, size_t ws_size,
                              hipStream_t stream) {
  const float* feat = (const float*)d_in[0];
  const int* labels = (const int*)d_in[1];
  float* out = (float*)d_out;

  float* norms = (float*)d_ws;       // [N]
  float* ap = norms + N;             // [N] running max over positives
  float* an = ap + N;                // [N] running min over negatives

  tl_pass0<<<N / 4, 256, 0, stream>>>(feat, norms, ap, an, out);

  dim3 grid1(JSPLIT, N / BI);        // 8 x 64 = 512 blocks, 2 per CU
  tl_pass1<<<grid1, 256, 0, stream>>>(feat, labels, norms,
                                      (unsigned int*)ap, (unsigned int*)an);

  tl_pass2<<<N / 256, 256, 0, stream>>>(ap, an, out);
}

// Round 2
// 126.677 us; speedup vs baseline: 4.2205x; 4.2205x over previous
//
#include <hip/hip_runtime.h>

// TripletLoss on MI355X — round 2: bf16-MFMA Gram matrix.
//
// loss = mean(relu(MARGIN + dist_ap - dist_an)), hard mining per row.
// Key ideas this round:
//  - feat (fp32) rounded RTN to bf16 once (pass0); Gram via mfma_f32_16x16x32_bf16.
//    Error budget: dist error ~1e-3 << 0.101 threshold (verified math in journal).
//  - Track t = nj - 2*dot per row (monotone in dist for fixed row): no sqrt in the
//    O(N^2) epilogue; sqrt/clamp/fallback handled once per row in pass2.
//  - m97-style staging: global_load_lds width=16, XOR-swizzled LDS granules
//    (16B granule g stored at g ^ (row&7)) -> 2-way bank aliasing only (free).
//  - Cross-block merge via order-preserving uint encoding + atomicMax/Min.

constexpr int N = 8192;
constexpr int D = 256;
constexpr float MARGIN = 0.3f;
constexpr float NEG_FALLBACK = 1e6f;
constexpr float TBIG = 1e30f;

typedef __attribute__((ext_vector_type(8))) __bf16 bf16x8;
typedef __attribute__((ext_vector_type(4))) float f32x4;

// Order-preserving float->uint encoding (works for negative values).
__device__ __forceinline__ unsigned enc_f(float f) {
  unsigned u = __float_as_uint(f);
  return (u >> 31) ? ~u : (u | 0x80000000u);
}
__device__ __forceinline__ float dec_f(unsigned e) {
  unsigned u = (e >> 31) ? (e ^ 0x80000000u) : ~e;
  return __uint_as_float(u);
}

__device__ __forceinline__ unsigned short f2bf_rtn(float x) {
  unsigned u = __float_as_uint(x);
  return (unsigned short)((u + 0x7fffu + ((u >> 16) & 1u)) >> 16);
}

// ---------------- fast path ----------------

__global__ void tl_pass0f(const float* __restrict__ feat, float* __restrict__ norms,
                          unsigned* __restrict__ ap, unsigned* __restrict__ an,
                          unsigned short* __restrict__ P, float* __restrict__ out) {
  int row = blockIdx.x * 4 + (threadIdx.x >> 6);
  int lane = threadIdx.x & 63;
  float4 f = reinterpret_cast<const float4*>(feat + (size_t)row * D)[lane];
  ushort4 h;
  h.x = f2bf_rtn(f.x); h.y = f2bf_rtn(f.y); h.z = f2bf_rtn(f.z); h.w = f2bf_rtn(f.w);
  reinterpret_cast<ushort4*>(P + (size_t)row * D)[lane] = h;
  float s = fmaf(f.x, f.x, fmaf(f.y, f.y, fmaf(f.z, f.z, f.w * f.w)));
#pragma unroll
  for (int off = 32; off > 0; off >>= 1) s += __shfl_down(s, off, 64);
  if (lane == 0) {
    norms[row] = s;
    ap[row] = enc_f(-TBIG);  // running max of t over positives
    an[row] = enc_f(TBIG);   // running min of t over negatives
  }
  if (row == 0 && lane == 0) out[0] = 0.0f;
}

__global__ __launch_bounds__(256, 3)
void tl_pass1m(const unsigned short* __restrict__ P, const int* __restrict__ labels,
               const float* __restrict__ norms,
               unsigned* __restrict__ ap, unsigned* __restrict__ an) {
  __shared__ unsigned short lA[128 * 64];
  __shared__ unsigned short lB[128 * 64];

  const int tid = threadIdx.x;
  const int wave = tid >> 6;
  const int lane = tid & 63;
  const int c = lane & 15;        // MFMA col-within-tile / row-read index
  const int q = lane >> 4;        // quad
  const int ib0 = blockIdx.y * 128;
  const int jb0 = blockIdx.x * 128;
  const int wi = (wave & 1) * 64; // wave's 64x64 region
  const int wj = (wave >> 1) * 64;

  f32x4 acc[4][4];
#pragma unroll
  for (int a = 0; a < 4; ++a)
#pragma unroll
    for (int b = 0; b < 4; ++b) acc[a][b] = (f32x4){0.f, 0.f, 0.f, 0.f};

  const int rsub = lane >> 3;                  // staging: 8 lanes per row
  const int gsw = (lane & 7) ^ (rsub & 7);     // swizzled source 16B-granule

  for (int kc = 0; kc < D; kc += 64) {
#pragma unroll
    for (int t = 0; t < 4; ++t) {
      int rA = wave * 32 + t * 8;  // 8 rows per instruction, contiguous LDS
      const unsigned short* gA = P + (size_t)(ib0 + rA + rsub) * D + kc + gsw * 8;
      __builtin_amdgcn_global_load_lds(
          (const __attribute__((address_space(1))) void*)gA,
          (__attribute__((address_space(3))) void*)&lA[rA * 64], 16, 0, 0);
      const unsigned short* gB = P + (size_t)(jb0 + rA + rsub) * D + kc + gsw * 8;
      __builtin_amdgcn_global_load_lds(
          (const __attribute__((address_space(1))) void*)gB,
          (__attribute__((address_space(3))) void*)&lB[rA * 64], 16, 0, 0);
    }
    __syncthreads();  // compiler drains vmcnt before s_barrier

#pragma unroll
    for (int ks = 0; ks < 2; ++ks) {
      bf16x8 af[4], bfr[4];
      const int gsel = ((ks * 4 + q) ^ (c & 7)) * 8;
#pragma unroll
      for (int a = 0; a < 4; ++a)
        af[a] = *(const bf16x8*)&lA[(wi + a * 16 + c) * 64 + gsel];
#pragma unroll
      for (int b = 0; b < 4; ++b)
        bfr[b] = *(const bf16x8*)&lB[(wj + b * 16 + c) * 64 + gsel];
#pragma unroll
      for (int a = 0; a < 4; ++a)
#pragma unroll
        for (int b = 0; b < 4; ++b)
          acc[a][b] = __builtin_amdgcn_mfma_f32_16x16x32_bf16(af[a], bfr[b], acc[a][b], 0, 0, 0);
    }
    __syncthreads();
  }

  // Epilogue: t = nj - 2*dot, masked per-row max(pos)/min(neg) in t-domain.
  int cj[4]; float nj[4]; int lj[4];
#pragma unroll
  for (int b = 0; b < 4; ++b) {
    cj[b] = jb0 + wj + b * 16 + c;
    nj[b] = norms[cj[b]];
    lj[b] = labels[cj[b]];
  }

  float* redAP = (float*)lA;          // 128 rows x 2 slots
  float* redAN = ((float*)lA) + 256;

#pragma unroll
  for (int a = 0; a < 4; ++a) {
#pragma unroll
    for (int r = 0; r < 4; ++r) {
      int rg = ib0 + wi + a * 16 + q * 4 + r;  // global row (C/D: row=quad*4+reg)
      int li = labels[rg];
      float tp = -TBIG, tn = TBIG;
#pragma unroll
      for (int b = 0; b < 4; ++b) {
        float t = fmaf(-2.f, acc[a][b][r], nj[b]);
        if (lj[b] == li) {
          if (cj[b] != rg) tp = fmaxf(tp, t);  // exclude diagonal by index
        } else {
          tn = fminf(tn, t);
        }
      }
      // reduce across the 16 lanes (columns) sharing this row
#pragma unroll
      for (int m = 1; m < 16; m <<= 1) {
        tp = fmaxf(tp, __shfl_xor(tp, m, 64));
        tn = fminf(tn, __shfl_xor(tn, m, 64));
      }
      if (c == 0) {
        int rl = wi + a * 16 + q * 4 + r;
        redAP[rl * 2 + (wave >> 1)] = tp;   // rows<64: waves 0,2; rows>=64: 1,3
        redAN[rl * 2 + (wave >> 1)] = tn;
      }
    }
  }
  __syncthreads();
  if (tid < 128) {
    float tp = fmaxf(redAP[tid * 2], redAP[tid * 2 + 1]);
    float tn = fminf(redAN[tid * 2], redAN[tid * 2 + 1]);
    atomicMax(&ap[ib0 + tid], enc_f(tp));
    atomicMin(&an[ib0 + tid], enc_f(tn));
  }
}

__global__ void tl_pass2f(const unsigned* __restrict__ ap, const unsigned* __restrict__ an,
                          const float* __restrict__ norms, float* __restrict__ out) {
  int r = blockIdx.x * 256 + threadIdx.x;
  float ni = norms[r];
  float tp = dec_f(ap[r]);
  float tn = dec_f(an[r]);
  float dap = (tp < -1e29f) ? 0.f : sqrtf(fmaxf(ni + tp, 0.f));
  float dan = (tn > 1e29f) ? NEG_FALLBACK : sqrtf(fmaxf(ni + tn, 0.f));
  float v = fmaxf(0.f, MARGIN + dap - dan) * (1.0f / (float)N);
#pragma unroll
  for (int off = 32; off > 0; off >>= 1) v += __shfl_down(v, off, 64);
  __shared__ float red[4];
  int lane = threadIdx.x & 63, w = threadIdx.x >> 6;
  if (lane == 0) red[w] = v;
  __syncthreads();
  if (threadIdx.x == 0) atomicAdd(out, red[0] + red[1] + red[2] + red[3]);
}

// ---------------- fallback fp32 path (small ws) — round-1 known-good ----------------

constexpr int FB_BK = 32;
constexpr int FB_JSPLIT = 8;
constexpr int FB_JRANGE = N / FB_JSPLIT;
constexpr int FB_LDS = 132;

__global__ void tl_pass0_fb(const float* __restrict__ feat, float* __restrict__ norms,
                            float* __restrict__ ap, float* __restrict__ an,
                            float* __restrict__ out) {
  int row = blockIdx.x * 4 + (threadIdx.x >> 6);
  int lane = threadIdx.x & 63;
  float4 f = reinterpret_cast<const float4*>(feat + (size_t)row * D)[lane];
  float s = f.x * f.x + f.y * f.y + f.z * f.z + f.w * f.w;
#pragma unroll
  for (int off = 32; off > 0; off >>= 1) s += __shfl_down(s, off, 64);
  if (lane == 0) { norms[row] = s; ap[row] = 0.0f; an[row] = NEG_FALLBACK; }
  if (row == 0 && lane == 0) out[0] = 0.0f;
}

__global__ __launch_bounds__(256, 2)
void tl_pass1_fb(const float* __restrict__ feat, const int* __restrict__ labels,
                 const float* __restrict__ norms,
                 unsigned int* __restrict__ ap, unsigned int* __restrict__ an) {
  __shared__ float As[FB_BK][FB_LDS];
  __shared__ float Bs[FB_BK][FB_LDS];
  const int tid = threadIdx.x;
  const int tx = tid & 15, ty = tid >> 4;
  const int ib0 = blockIdx.y * 128;
  const int jbase = blockIdx.x * FB_JRANGE;
  float ni[8]; int li[8]; int ri[8];
#pragma unroll
  for (int a = 0; a < 8; ++a) {
    int r = ty * 4 + (a & 3) + ((a >> 2) << 6);
    ri[a] = ib0 + r; ni[a] = norms[ri[a]]; li[a] = labels[ri[a]];
  }
  float apv[8], anv[8];
#pragma unroll
  for (int a = 0; a < 8; ++a) { apv[a] = 0.0f; anv[a] = NEG_FALLBACK; }
  for (int jt = 0; jt < FB_JRANGE; jt += 128) {
    const int jb = jbase + jt;
    float acc[8][8];
#pragma unroll
    for (int a = 0; a < 8; ++a)
#pragma unroll
      for (int b = 0; b < 8; ++b) acc[a][b] = 0.0f;
    for (int kc = 0; kc < D; kc += FB_BK) {
#pragma unroll
      for (int u = 0; u < 4; ++u) {
        int lin = tid + u * 256;
        int row = lin >> 3, c4 = lin & 7;
        float4 va = *reinterpret_cast<const float4*>(feat + (size_t)(ib0 + row) * D + kc + c4 * 4);
        As[c4 * 4 + 0][row] = va.x; As[c4 * 4 + 1][row] = va.y;
        As[c4 * 4 + 2][row] = va.z; As[c4 * 4 + 3][row] = va.w;
        float4 vb = *reinterpret_cast<const float4*>(feat + (size_t)(jb + row) * D + kc + c4 * 4);
        Bs[c4 * 4 + 0][row] = vb.x; Bs[c4 * 4 + 1][row] = vb.y;
        Bs[c4 * 4 + 2][row] = vb.z; Bs[c4 * 4 + 3][row] = vb.w;
      }
      __syncthreads();
#pragma unroll 8
      for (int k = 0; k < FB_BK; ++k) {
        float4 a0 = *reinterpret_cast<const float4*>(&As[k][ty * 4]);
        float4 a1 = *reinterpret_cast<const float4*>(&As[k][64 + ty * 4]);
        float4 b0 = *reinterpret_cast<const float4*>(&Bs[k][tx * 4]);
        float4 b1 = *reinterpret_cast<const float4*>(&Bs[k][64 + tx * 4]);
        float av[8] = {a0.x, a0.y, a0.z, a0.w, a1.x, a1.y, a1.z, a1.w};
        float bv[8] = {b0.x, b0.y, b0.z, b0.w, b1.x, b1.y, b1.z, b1.w};
#pragma unroll
        for (int a = 0; a < 8; ++a)
#pragma unroll
          for (int b = 0; b < 8; ++b) acc[a][b] = fmaf(av[a], bv[b], acc[a][b]);
      }
      __syncthreads();
    }
#pragma unroll
    for (int b = 0; b < 8; ++b) {
      int cjx = jb + tx * 4 + (b & 3) + ((b >> 2) << 6);
      float njx = norms[cjx]; int ljx = labels[cjx];
#pragma unroll
      for (int a = 0; a < 8; ++a) {
        float sq = fmaxf(ni[a] + njx - 2.0f * acc[a][b], 0.0f);
        float dist = sqrtf(sq);
        if (li[a] == ljx) { if (ri[a] != cjx) apv[a] = fmaxf(apv[a], dist); }
        else anv[a] = fminf(anv[a], dist);
      }
    }
  }
  __syncthreads();
  float* red = &As[0][0];
#pragma unroll
  for (int a = 0; a < 8; ++a) {
    int r = ty * 4 + (a & 3) + ((a >> 2) << 6);
    red[r * 16 + tx] = apv[a];
  }
  __syncthreads();
  if (tid < 128) {
    float m = red[tid * 16];
#pragma unroll
    for (int t = 1; t < 16; ++t) m = fmaxf(m, red[tid * 16 + t]);
    atomicMax(&ap[ib0 + tid], __float_as_uint(m));
  }
  __syncthreads();
#pragma unroll
  for (int a = 0; a < 8; ++a) {
    int r = ty * 4 + (a & 3) + ((a >> 2) << 6);
    red[r * 16 + tx] = anv[a];
  }
  __syncthreads();
  if (tid < 128) {
    float m = red[tid * 16];
#pragma unroll
    for (int t = 1; t < 16; ++t) m = fminf(m, red[tid * 16 + t]);
    atomicMin(&an[ib0 + tid], __float_as_uint(m));
  }
}

__global__ void tl_pass2_fb(const float* __restrict__ ap, const float* __restrict__ an,
                            float* __restrict__ out) {
  int r = blockIdx.x * 256 + threadIdx.x;
  float v = fmaxf(0.0f, MARGIN + ap[r] - an[r]) * (1.0f / (float)N);
#pragma unroll
  for (int off = 32; off > 0; off >>= 1) v += __shfl_down(v, off, 64);
  __shared__ float red[4];
  int lane = threadIdx.x & 63, w = threadIdx.x >> 6;
  if (lane == 0) red[w] = v;
  __syncthreads();
  if (threadIdx.x == 0) atomicAdd(out, red[0] + red[1] + red[2] + red[3]);
}

// ---------------- launch ----------------

extern "C" void kernel_launch(void* const* d_in, const int* in_sizes, int n_in,
                              void* d_out, int out_size, void* d_ws, size_t ws_size,
                              hipStream_t stream) {
  const float* feat = (const float*)d_in[0];
  const int* labels = (const int*)d_in[1];
  float* out = (float*)d_out;

  // ws layout (fast): norms[8192] f32 | ap_enc[8192] u32 | an_enc[8192] u32 | P[8192*256] bf16
  float* norms = (float*)d_ws;
  unsigned* ap = (unsigned*)(norms + N);
  unsigned* an = ap + N;
  unsigned short* P = (unsigned short*)(an + N);
  const size_t NEED = 3 * (size_t)N * 4 + (size_t)N * D * 2;

  if (ws_size >= NEED) {
    tl_pass0f<<<N / 4, 256, 0, stream>>>(feat, norms, ap, an, P, out);
    dim3 grid1(N / 128, N / 128);  // 64 x 64
    tl_pass1m<<<grid1, 256, 0, stream>>>(P, labels, norms, ap, an);
    tl_pass2f<<<N / 256, 256, 0, stream>>>(ap, an, norms, out);
  } else {
    float* apf = (float*)ap;
    float* anf = (float*)an;
    tl_pass0_fb<<<N / 4, 256, 0, stream>>>(feat, norms, apf, anf, out);
    dim3 grid1(FB_JSPLIT, N / 128);
    tl_pass1_fb<<<grid1, 256, 0, stream>>>(feat, labels, norms, (unsigned*)apf, (unsigned*)anf);
    tl_pass2_fb<<<N / 256, 256, 0, stream>>>(apf, anf, out);
  }
}